// Round 17
// baseline (1257.299 us; speedup 1.0000x reference)
//
#include <hip/hip_runtime.h>
#include <hip/hip_bf16.h>
#include <cstdint>
#include <cstddef>

#define B_    8
#define S_    2048
#define D_    1024
#define DFF_  4096
#define E1_   8
#define E2_   16
#define T_    (B_*S_)
#define CAP1_ 2560
#define CAP2_ 1280
#define EC_   20480   // E1_*CAP1_ == E2_*CAP2_ == padded expert-buffer rows

typedef float f32x4 __attribute__((ext_vector_type(4)));

__device__ __forceinline__ unsigned int pk4fp8(float a, float b, float c, float d) {
  int r = __builtin_amdgcn_cvt_pk_fp8_f32(a, b, 0, false);
  r = __builtin_amdgcn_cvt_pk_fp8_f32(c, d, r, true);
  return (unsigned int)r;
}

// ------- gating: logits = X @ WG, softmax-max + argmax (+opt. wtrans workers) --
template<int E>
__global__ __launch_bounds__(256)
void gate_kernel(const float* __restrict__ X, const float* __restrict__ WG,
                 int* __restrict__ idxO, float* __restrict__ gateO,
                 const float* __restrict__ tsrc, unsigned char* __restrict__ tdst,
                 int tK, int tN, int tE, int nwrk) {
  __shared__ char tsm[16384];
  const int tid = threadIdx.x;

  // ---- transpose-worker blocks: f32 [tE][tK][tN] -> fp8 [tE][tN][tK] ----
  // 256 threads: 2 threads per row (krow 0..127), each covers a 64-col half.
  if (tsrc != nullptr && (int)blockIdx.x < nwrk) {
    const int ntn = tN >> 7, ntk = tK >> 7;
    const int tiles = tE * ntk * ntn;
    const int krow = tid >> 1;            // 0..127
    const int kq   = (tid & 1) * 64;      // 64-elem half
    for (int t = blockIdx.x; t < tiles; t += nwrk) {
      const int e2 = t / (ntk * ntn), rm = t - e2 * (ntk * ntn);
      const int k0 = (rm / ntn) << 7, n0 = (rm - (rm / ntn) * ntn) << 7;
      const float* s = tsrc + (size_t)e2 * tK * tN + (size_t)(k0 + krow) * tN + n0 + kq;
#pragma unroll
      for (int j = 0; j < 16; ++j) {
        float4 v = *(const float4*)(s + j * 4);
        unsigned int q = pk4fp8(v.x, v.y, v.z, v.w);
#pragma unroll
        for (int b = 0; b < 4; ++b)
          tsm[(kq + j * 4 + b) * 128 + krow] = (char)((q >> (8 * b)) & 0xff);
      }
      __syncthreads();
      unsigned char* d = tdst + (size_t)e2 * tK * tN + (size_t)(n0 + krow) * tK + k0 + kq;
#pragma unroll
      for (int i = 0; i < 4; ++i)
        *(uint4*)(d + 16 * i) = *(const uint4*)(tsm + krow * 128 + kq + 16 * i);
      __syncthreads();
    }
    return;
  }

  const int gb   = (int)blockIdx.x - ((tsrc != nullptr) ? nwrk : 0);
  const int lane = tid & 63;
  const int wv   = tid >> 6;
  const int t    = gb * 4 + wv;
  const float* xr = X + (size_t)t * D_;
  float acc[E];
#pragma unroll
  for (int e = 0; e < E; ++e) acc[e] = 0.f;
#pragma unroll
  for (int i = 0; i < 4; ++i) {
    float4 xv = *(const float4*)(xr + i * 256 + lane * 4);
    int kb = i * 256 + lane * 4;
#pragma unroll
    for (int j = 0; j < 4; ++j) {
      float xs = (&xv.x)[j];
      const float* wr = WG + (size_t)(kb + j) * E;
#pragma unroll
      for (int e = 0; e < E; ++e) acc[e] += xs * wr[e];
    }
  }
#pragma unroll
  for (int e = 0; e < E; ++e) {
    float v = acc[e];
#pragma unroll
    for (int s = 32; s >= 1; s >>= 1) v += __shfl_xor(v, s, 64);
    acc[e] = v;
  }
  if (lane == 0) {
    float mx = acc[0]; int mi = 0;
#pragma unroll
    for (int e = 1; e < E; ++e) if (acc[e] > mx) { mx = acc[e]; mi = e; }
    float s = 0.f;
#pragma unroll
    for (int e = 0; e < E; ++e) s += expf(acc[e] - mx);
    idxO[t]  = mi;
    gateO[t] = 1.0f / s;   // max softmax prob
  }
}

// ---------------- order-preserving per-expert position scan ----------------
__global__ __launch_bounds__(1024)
void scan_kernel(const int* __restrict__ idx, int E, int cap,
                 int* __restrict__ pos, int* __restrict__ kept) {
  __shared__ int cnt[16][17];
  __shared__ int gbase[16];
  const int tid = threadIdx.x;
  const int w = tid >> 6, lane = tid & 63;
  if (tid < E) gbase[tid] = 0;
  __syncthreads();
  const unsigned long long lt = (lane == 63) ? 0xFFFFFFFFFFFFFFFFull >> 1
                                             : ((1ull << lane) - 1ull);
  for (int it = 0; it < T_ / 1024; ++it) {
    int t = it * 1024 + tid;
    int mi = idx[t];
    int rank = 0;
    for (int e = 0; e < E; ++e) {
      unsigned long long m = __ballot(mi == e);
      if (lane == 0) cnt[w][e] = __popcll(m);
      if (mi == e) rank = __popcll(m & lt);
    }
    __syncthreads();
    int off = 0;
    for (int w2 = 0; w2 < w; ++w2) off += cnt[w2][mi];
    pos[t] = gbase[mi] + off + rank;
    __syncthreads();
    if (tid < E) {
      int tot = 0;
      for (int w2 = 0; w2 < 16; ++w2) tot += cnt[w2][tid];
      gbase[tid] += tot;
    }
    __syncthreads();
  }
  if (tid < E) kept[tid] = min(gbase[tid], cap);
}

// -- scatter tokens to expert buffers (f32 -> fp8); zero m-row for DROPPED only -
__global__ __launch_bounds__(256)
void scatter_kernel(const float* __restrict__ X, const int* __restrict__ idx,
                    const int* __restrict__ pos, int cap,
                    unsigned char* __restrict__ xbuf, int* __restrict__ tokmap,
                    float* __restrict__ mzero) {
  const int t = blockIdx.x * 4 + (threadIdx.x >> 6);
  const int lane = threadIdx.x & 63;
  const int p = pos[t];
  if (p < cap) {
    const size_t dst = ((size_t)idx[t] * cap + p) * D_;
    const float* xr = X + (size_t)t * D_;
#pragma unroll
    for (int i = 0; i < 4; ++i) {
      float4 v = *(const float4*)(xr + i * 256 + lane * 4);
      *(unsigned int*)(xbuf + dst + i * 256 + lane * 4) = pk4fp8(v.x, v.y, v.z, v.w);
    }
    if (lane == 0) tokmap[(size_t)idx[t] * cap + p] = t;
  } else {
    float4 z = {0.f, 0.f, 0.f, 0.f};
    float* mr = mzero + (size_t)t * D_;
#pragma unroll
    for (int i = 0; i < 4; ++i) *(float4*)(mr + i * 256 + lane * 4) = z;
  }
}

// ---------------- expert GEMM: 256x256 tile, fp8 BK=128, 8-phase counted-vmcnt -
// GEMM path identical to rounds 14/15 (absmax-0.0 verified). Worker blocks:
//  - tsrc != null: transpose next weight f32 -> fp8 (512-thr indexing, r15-verified).
//  - xsrc != null: pre-accumulate residual x-mean into sentx (backfills GEMM1_2).
#define STG(BASEPTR, H, KT, SLOT) do {                                          \
    const unsigned char* _s = (BASEPTR) + (size_t)((H) * 128) * K + (KT) + st_off; \
    __builtin_amdgcn_global_load_lds((const __attribute__((address_space(1))) void*)_s, \
        (__attribute__((address_space(3))) void*)(smem + (SLOT) + dst0), 16, 0, 0);   \
    __builtin_amdgcn_global_load_lds((const __attribute__((address_space(1))) void*)(_s + (size_t)64 * K), \
        (__attribute__((address_space(3))) void*)(smem + (SLOT) + 8192 + dst0), 16, 0, 0); \
  } while (0)

#define RDA(BUF, MH) do { _Pragma("unroll")                                     \
    for (int m_ = 0; m_ < 4; ++m_) {                                            \
      const char* _p = smem + (BUF) * 65536 + aslot + ((MH) * 4 + m_) * 2048 + vaf; \
      _Pragma("unroll") for (int k_ = 0; k_ < 4; ++k_)                          \
        af[m_][k_] = *(const long long*)(_p + (((2 * k_ + c0) ^ swz7) << 4)); } } while (0)

#define RDB01(BUF, DEST) do { _Pragma("unroll")                                 \
    for (int j_ = 0; j_ < 2; ++j_) {                                            \
      const char* _p = smem + (BUF) * 65536 + bslot + j_ * 2048 + vbf;          \
      _Pragma("unroll") for (int k_ = 0; k_ < 4; ++k_)                          \
        DEST[j_][k_] = *(const long long*)(_p + (((2 * k_ + c0) ^ swz7) << 4)); } } while (0)

#define RDB23(BUF) do { _Pragma("unroll")                                       \
    for (int j_ = 0; j_ < 2; ++j_) {                                            \
      const char* _p = smem + (BUF) * 65536 + bslot + (2 + j_) * 2048 + vbf;    \
      _Pragma("unroll") for (int k_ = 0; k_ < 4; ++k_)                          \
        bfb[j_][k_] = *(const long long*)(_p + (((2 * k_ + c0) ^ swz7) << 4)); } } while (0)

#define QUADN0(MH, BA) do {                                                     \
    __builtin_amdgcn_s_setprio(1);                                              \
    _Pragma("unroll") for (int m_ = 0; m_ < 4; ++m_)                            \
    _Pragma("unroll") for (int j_ = 0; j_ < 2; ++j_)                            \
    _Pragma("unroll") for (int k_ = 0; k_ < 4; ++k_)                            \
      acc[(MH) * 4 + m_][j_] = __builtin_amdgcn_mfma_f32_16x16x32_fp8_fp8(      \
          af[m_][k_], BA[j_][k_], acc[(MH) * 4 + m_][j_], 0, 0, 0);             \
    __builtin_amdgcn_s_setprio(0);                                              \
  } while (0)

#define QUADN1(MH) do {                                                         \
    __builtin_amdgcn_s_setprio(1);                                              \
    _Pragma("unroll") for (int m_ = 0; m_ < 4; ++m_)                            \
    _Pragma("unroll") for (int j_ = 0; j_ < 2; ++j_)                            \
    _Pragma("unroll") for (int k_ = 0; k_ < 4; ++k_)                            \
      acc[(MH) * 4 + m_][2 + j_] = __builtin_amdgcn_mfma_f32_16x16x32_fp8_fp8(  \
          af[m_][k_], bfb[j_][k_], acc[(MH) * 4 + m_][2 + j_], 0, 0, 0);        \
    __builtin_amdgcn_s_setprio(0);                                              \
  } while (0)

#define SB0   __builtin_amdgcn_sched_barrier(0)
#define BAR   __builtin_amdgcn_s_barrier()
#define VM6   do { asm volatile("s_waitcnt vmcnt(6)" ::: "memory"); SB0; } while (0)
#define VM8   do { asm volatile("s_waitcnt vmcnt(8)" ::: "memory"); SB0; } while (0)
#define VM0   do { asm volatile("s_waitcnt vmcnt(0)" ::: "memory"); SB0; } while (0)

template<int MODE>
__global__ __launch_bounds__(512, 2)
void moe_gemm(const unsigned char* __restrict__ A,
              const unsigned char* __restrict__ BT,
              const float* __restrict__ bias, int K, int N, int cap, int nbcnt,
              int ntl,
              const int* __restrict__ kept,
              unsigned char* __restrict__ Hout, float* __restrict__ Mout,
              const int* __restrict__ tokmap, const float* __restrict__ gate,
              const float* __restrict__ tsrc, unsigned char* __restrict__ tdst,
              int tK, int tN, int tE,
              const float* __restrict__ xsrc, float* __restrict__ sentx,
              int nwrk) {
  __shared__ char smem[131072];
  const int tid  = threadIdx.x;

  // ---- transpose-worker blocks (co-run with GEMM blocks; 512-thr indexing) ----
  if (tsrc != nullptr && (int)blockIdx.x < nwrk) {
    const int ntn = tN >> 7, ntk = tK >> 7;
    const int tiles = tE * ntk * ntn;
    const int krow = tid >> 2;            // 0..127
    const int kq   = (tid & 3) * 32;      // 32-elem quarter
    for (int t = blockIdx.x; t < tiles; t += nwrk) {
      const int e2 = t / (ntk * ntn), rm = t - e2 * (ntk * ntn);
      const int k0 = (rm / ntn) << 7, n0 = (rm - (rm / ntn) * ntn) << 7;
      const float* s = tsrc + (size_t)e2 * tK * tN + (size_t)(k0 + krow) * tN + n0 + kq;
#pragma unroll
      for (int j = 0; j < 8; ++j) {
        float4 v = *(const float4*)(s + j * 4);
        unsigned int q = pk4fp8(v.x, v.y, v.z, v.w);
#pragma unroll
        for (int b = 0; b < 4; ++b)
          smem[(kq + j * 4 + b) * 128 + krow] = (char)((q >> (8 * b)) & 0xff);
      }
      __syncthreads();
      unsigned char* d = tdst + (size_t)e2 * tK * tN + (size_t)(n0 + krow) * tK + k0 + kq;
      *(uint4*)(d)      = *(const uint4*)(smem + krow * 128 + kq);
      *(uint4*)(d + 16) = *(const uint4*)(smem + krow * 128 + kq + 16);
      __syncthreads();
    }
    return;
  }

  // ---- x-mean worker blocks: sentx[b][c] += mean_s x[b][s][c] (x part) ----
  if (xsrc != nullptr && (int)blockIdx.x < nwrk) {
    const int b  = blockIdx.x >> 3;       // 0..7
    const int se = blockIdx.x & 7;        // s-eighth
    const float* xr = xsrc + ((size_t)b * S_ + (size_t)se * 256) * D_;
    float ax = 0.f, ay = 0.f;
    const int c2 = tid * 2;
    for (int s = 0; s < 256; ++s) {
      float2 v = *(const float2*)(xr + (size_t)s * D_ + c2);
      ax += v.x; ay += v.y;
    }
    atomicAdd(&sentx[b * D_ + c2],     ax * (1.0f / (float)S_));
    atomicAdd(&sentx[b * D_ + c2 + 1], ay * (1.0f / (float)S_));
    return;
  }

  const int gbid = (int)blockIdx.x - ((tsrc != nullptr || xsrc != nullptr) ? nwrk : 0);
  const int lane = tid & 63;
  const int wv   = tid >> 6;      // 0..7
  const int wr   = wv >> 2;       // 0..1 (M half)
  const int wc   = wv & 3;        // 0..3 (N quarter)

  // XCD-chunk swizzle + group-of-4-mb for L2 locality (over GEMM tiles only)
  const int wg  = (gbid & 7) * (ntl >> 3) + (gbid >> 3);
  const int per_grp = nbcnt * 4;
  const int grp = wg / per_grp;
  const int rem = wg - grp * per_grp;
  const int mb  = grp * 4 + (rem & 3);
  const int nb  = rem >> 2;

  const int e  = (mb * 256) / cap;
  const int r0 = mb * 256 - e * cap;
  const int kept_e = kept[e];
  if (r0 >= kept_e) return;
  const unsigned char* Ab = A + (size_t)(mb * 256) * K;
  const unsigned char* Bb = BT + ((size_t)e * N + (size_t)nb * 256) * K;

  f32x4 acc[8][4];
#pragma unroll
  for (int m = 0; m < 8; ++m)
#pragma unroll
    for (int n = 0; n < 4; ++n) acc[m][n] = (f32x4){0.f, 0.f, 0.f, 0.f};

  // staging: chunk row = tid>>3 (0..63), cc = tid&7; 16B chunks, src pre-swizzled
  const int scol   = ((tid & 7) ^ ((tid >> 3) & 7)) * 16;   // fp8 elements (=bytes)
  const size_t st_off = (size_t)(tid >> 3) * K + scol;
  const int dst0   = tid * 16;

  // fragment read addressing (fp8, b64 per frag)
  const int r16  = lane & 15;
  const int l34  = lane >> 4;                 // 0..3
  const int c0   = l34 >> 1;                  // chunk base within window pair
  const int swz7 = r16 & 7;
  const int vaf  = r16 * 128 + (l34 & 1) * 8;
  const int vbf  = (wc & 1) * 8192 + vaf;
  const int aslot = wr * 16384;
  const int bslot = 32768 + (wc >> 1) * 16384;
  long long af[4][4], bA0[2][4], bA1[2][4], bfb[2][4];

  // slot byte offsets: buf0 A0=0 A1=16384 B0=32768 B1=49152 ; buf1 +65536
  // prologue: stage buf0{A0,B0,B1,A1}, buf1{A0,B0,B1,A1} (K-tiles 0 and 128)
  STG(Ab, 0, 0, 0);
  STG(Bb, 0, 0, 32768);
  STG(Bb, 1, 0, 49152);
  STG(Ab, 1, 0, 16384);
  STG(Ab, 0, 128, 65536);
  STG(Bb, 0, 128, 98304);
  STG(Bb, 1, 128, 114688);
  STG(Ab, 1, 128, 81920);
  VM8; BAR;   // buf0's 8 loads landed; buf1's 8 outstanding
  RDB01(0, bA0);   // buf0 B-frags 0,1 (landed)

  const int NT = K >> 7;   // 128-wide K-tiles
  const int NI = K >> 8;   // 2 K-tiles per iteration
  for (int i = 0; i < NI; ++i) {
    const bool last = (i == NI - 1);
    const bool s2 = (2 * i + 2) < NT;   // stage tile 2i+2 (into buf0)
    const bool s3 = (2 * i + 3) < NT;   // stage tile 2i+3 (into buf1)
    const int kt1 = (2 * i + 1) << 7;
    const int kt2 = (2 * i + 2) << 7;
    const int kt3 = (2 * i + 3) << 7;

    // ph1: reads buf0.A0 (B01 already in bA0) ; stage buf1.A1 <- tile 2i+1
    RDA(0, 0);
    if (i > 0) STG(Ab, 1, kt1, 81920);
    BAR; QUADN0(0, bA0); BAR;
    // ph2: reads buf0 B-frags 2,3 ; stage buf0.A0 <- tile 2i+2
    RDB23(0);
    if (s2) STG(Ab, 0, kt2, 0);
    BAR; QUADN1(0); BAR;
    // ph3: reads buf0.A1 ; stage buf0.B0 <- tile 2i+2
    RDA(0, 1);
    if (s2) STG(Bb, 0, kt2, 32768);
    BAR; QUADN1(1); BAR;
    // ph4: stage buf0.B1 <- tile 2i+2 ; checkpoint ; pre-read buf1 B-frags 0,1
    if (s2) STG(Bb, 1, kt2, 49152);
    if (last) { VM0; } else { VM6; }
    RDB01(1, bA1);
    BAR; QUADN0(1, bA0); BAR;
    // ph5: reads buf1.A0 ; stage buf0.A1 <- tile 2i+2
    RDA(1, 0);
    if (s2) STG(Ab, 1, kt2, 16384);
    BAR; QUADN0(0, bA1); BAR;
    // ph6: reads buf1 B-frags 2,3 ; stage buf1.A0 <- tile 2i+3
    RDB23(1);
    if (s3) STG(Ab, 0, kt3, 65536);
    BAR; QUADN1(0); BAR;
    // ph7: reads buf1.A1 ; stage buf1.B0 <- tile 2i+3
    RDA(1, 1);
    if (s3) STG(Bb, 0, kt3, 98304);
    BAR; QUADN1(1); BAR;
    // ph8: stage buf1.B1 <- tile 2i+3 ; checkpoint ; pre-read buf0 B-frags 0,1
    if (s3) STG(Bb, 1, kt3, 114688);
    if (!last) { VM6; RDB01(0, bA0); }
    BAR; QUADN0(1, bA1); BAR;
  }

  // epilogue
  const int rg = lane >> 4;
  float bv[4];
#pragma unroll
  for (int n = 0; n < 4; ++n)
    bv[n] = bias[(size_t)e * N + nb * 256 + wc * 64 + n * 16 + r16];

#pragma unroll
  for (int m = 0; m < 8; ++m) {
#pragma unroll
    for (int r = 0; r < 4; ++r) {
      const int lrow = wr * 128 + m * 16 + rg * 4 + r;
      if (MODE == 0) {
        unsigned char* orow = Hout + (size_t)(mb * 256 + lrow) * N + nb * 256;
        unsigned int q = pk4fp8(fmaxf(acc[m][0][r] + bv[0], 0.f),
                                fmaxf(acc[m][1][r] + bv[1], 0.f),
                                fmaxf(acc[m][2][r] + bv[2], 0.f),
                                fmaxf(acc[m][3][r] + bv[3], 0.f));
        orow[wc * 64 +  0 + r16] = (unsigned char)(q & 0xff);
        orow[wc * 64 + 16 + r16] = (unsigned char)((q >> 8) & 0xff);
        orow[wc * 64 + 32 + r16] = (unsigned char)((q >> 16) & 0xff);
        orow[wc * 64 + 48 + r16] = (unsigned char)(q >> 24);
      } else {
        const int lr = r0 + lrow;
        if (lr < kept_e) {
          const int tok = tokmap[mb * 256 + lrow];
          const float gsc = gate[tok];
          float* orow = Mout + (size_t)tok * N + nb * 256;
#pragma unroll
          for (int n = 0; n < 4; ++n)
            orow[wc * 64 + n * 16 + r16] = (acc[m][n][r] + bv[n]) * gsc;
        }
      }
    }
  }
}

// ---------------- residual mean: m2 part only (x part done by GEMM workers) ---
__global__ __launch_bounds__(256)
void reduce_kernel(const float* __restrict__ M2, float* __restrict__ sent) {
  const int c = blockIdx.x * 256 + threadIdx.x;   // 0..1023
  const int b = blockIdx.z;
  const int s0 = blockIdx.y * 128;
  float a = 0.f;
  size_t base = ((size_t)b * S_ + s0) * D_ + c;
  for (int s = 0; s < 128; ++s) a += M2[base + (size_t)s * D_];
  atomicAdd(&sent[b * D_ + c], a * (1.0f / (float)S_));
}

// ---------------- logsumexp NLL loss ----------------
__global__ __launch_bounds__(64)
void loss_kernel(const float* __restrict__ sent, const int* __restrict__ y,
                 float* __restrict__ out) {
  const int lane = threadIdx.x;
  float total = 0.f;
  for (int b = 0; b < B_; ++b) {
    const float* s = sent + b * D_;
    float v[16];
    float mx = -1e30f;
#pragma unroll
    for (int i = 0; i < 16; ++i) { v[i] = s[lane + i * 64]; mx = fmaxf(mx, v[i]); }
#pragma unroll
    for (int sh = 32; sh >= 1; sh >>= 1) mx = fmaxf(mx, __shfl_xor(mx, sh, 64));
    float sm = 0.f;
#pragma unroll
    for (int i = 0; i < 16; ++i) sm += expf(v[i] - mx);
#pragma unroll
    for (int sh = 32; sh >= 1; sh >>= 1) sm += __shfl_xor(sm, sh, 64);
    total += logf(sm) + mx - s[y[b]];
  }
  if (lane == 0) out[0] = total * (1.0f / (float)B_);
}

extern "C" void kernel_launch(void* const* d_in, const int* in_sizes, int n_in,
                              void* d_out, int out_size, void* d_ws, size_t ws_size,
                              hipStream_t stream) {
  const float* x   = (const float*)d_in[0];
  const int*   y   = (const int*)d_in[1];
  const float* wg1 = (const float*)d_in[2];
  const float* w1a = (const float*)d_in[3];
  const float* b1a = (const float*)d_in[4];
  const float* w2a = (const float*)d_in[5];
  const float* b2a = (const float*)d_in[6];
  const float* wg2 = (const float*)d_in[7];
  const float* w1b = (const float*)d_in[8];
  const float* b1b = (const float*)d_in[9];
  const float* w2b = (const float*)d_in[10];
  const float* b2b = (const float*)d_in[11];
  float* out = (float*)d_out;
  (void)in_sizes; (void)n_in; (void)out_size; (void)ws_size;

  char* base = (char*)d_ws;
  size_t o = 0;
  auto alloc = [&](size_t bytes) { size_t r = o; o = (o + bytes + 255) & ~(size_t)255; return r; };
  int*   idx1    = (int*)  (base + alloc((size_t)T_ * 4));
  int*   pos1    = (int*)  (base + alloc((size_t)T_ * 4));
  float* gate1   = (float*)(base + alloc((size_t)T_ * 4));
  int*   idx2    = (int*)  (base + alloc((size_t)T_ * 4));
  int*   pos2    = (int*)  (base + alloc((size_t)T_ * 4));
  float* gate2   = (float*)(base + alloc((size_t)T_ * 4));
  int*   kept1   = (int*)  (base + alloc(64 * 4));
  int*   kept2   = (int*)  (base + alloc(64 * 4));
  int*   tokmap1 = (int*)  (base + alloc((size_t)EC_ * 4));
  int*   tokmap2 = (int*)  (base + alloc((size_t)EC_ * 4));
  float* sent    = (float*)(base + alloc((size_t)B_ * D_ * 4));
  float* m1      = (float*)(base + alloc((size_t)T_ * D_ * 4));   // layer-1 out, reused as layer-2 out
  unsigned char* xbuf = (unsigned char*)(base + alloc((size_t)EC_ * D_));        // 20 MB fp8
  unsigned char* h    = (unsigned char*)(base + alloc((size_t)EC_ * DFF_));      // 80 MB fp8
  unsigned char* P1   = (unsigned char*)(base + alloc((size_t)E2_ * D_ * DFF_)); // 64 MB fp8
  unsigned char* P2   = (unsigned char*)(base + alloc((size_t)E2_ * D_ * DFF_)); // 64 MB fp8

  hipMemsetAsync(sent, 0, (size_t)B_ * D_ * 4, stream);

  const int NT0 = (DFF_ / 256) * (EC_ / 256);   // 1280 GEMM0 tiles
  const int NT1 = (D_  / 256) * (EC_ / 256);    // 320  GEMM1 tiles
  const int NW  = 128;                          // transpose-worker blocks

  // ----- layer 1 (E=8, cap=2560) -----
  // gate1 carries the w1a -> P1 transpose as worker blocks (both independent)
  gate_kernel<E1_><<<T_ / 4 + NW, 256, 0, stream>>>(x, wg1, idx1, gate1,
                                                    w1a, P1, D_, DFF_, E1_, NW);
  scan_kernel<<<1, 1024, 0, stream>>>(idx1, E1_, CAP1_, pos1, kept1);
  scatter_kernel<<<T_ / 4, 256, 0, stream>>>(x, idx1, pos1, CAP1_, xbuf, tokmap1, m1);
  // GEMM0_1 reads P1(w1a^T); workers transpose w2a -> P2
  moe_gemm<0><<<NT0 + NW, 512, 0, stream>>>(
      xbuf, P1, b1a, D_, DFF_, CAP1_, DFF_ / 256, NT0, kept1, h, nullptr, nullptr, nullptr,
      w2a, P2, DFF_, D_, E1_, nullptr, nullptr, NW);
  // GEMM1_1 reads P2(w2a^T); workers transpose w1b -> P1
  moe_gemm<1><<<NT1 + NW, 512, 0, stream>>>(
      h, P2, b2a, DFF_, D_, CAP1_, D_ / 256, NT1, kept1, nullptr, m1, tokmap1, gate1,
      w1b, P1, D_, DFF_, E2_, nullptr, nullptr, NW);

  // ----- layer 2 (E=16, cap=1280) -----
  gate_kernel<E2_><<<T_ / 4, 256, 0, stream>>>(m1, wg2, idx2, gate2,
                                               nullptr, nullptr, 0, 0, 0, 0);
  scan_kernel<<<1, 1024, 0, stream>>>(idx2, E2_, CAP2_, pos2, kept2);
  scatter_kernel<<<T_ / 4, 256, 0, stream>>>(m1, idx2, pos2, CAP2_, xbuf, tokmap2, m1);
  // GEMM0_2 reads P1(w1b^T); workers transpose w2b -> P2
  moe_gemm<0><<<NT0 + NW, 512, 0, stream>>>(
      xbuf, P1, b1b, D_, DFF_, CAP2_, DFF_ / 256, NT0, kept2, h, nullptr, nullptr, nullptr,
      w2b, P2, DFF_, D_, E2_, nullptr, nullptr, NW);
  // GEMM1_2 reads P2(w2b^T); workers pre-accumulate x-mean into sent
  moe_gemm<1><<<NT1 + 64, 512, 0, stream>>>(
      h, P2, b2b, DFF_, D_, CAP2_, D_ / 256, NT1, kept2, nullptr, m1, tokmap2, gate2,
      nullptr, nullptr, 0, 0, 0, x, sent, 64);

  // ----- residual (m2 part) + loss -----
  reduce_kernel<<<dim3(D_ / 256, S_ / 128, B_), 256, 0, stream>>>(m1, sent);
  loss_kernel<<<1, 64, 0, stream>>>(sent, y, out);
}

// Round 18
// 1241.727 us; speedup vs baseline: 1.0125x; 1.0125x over previous
//
#include <hip/hip_runtime.h>
#include <hip/hip_bf16.h>
#include <cstdint>
#include <cstddef>

#define B_    8
#define S_    2048
#define D_    1024
#define DFF_  4096
#define E1_   8
#define E2_   16
#define T_    (B_*S_)
#define CAP1_ 2560
#define CAP2_ 1280
#define EC_   20480   // E1_*CAP1_ == E2_*CAP2_ == padded expert-buffer rows

typedef float f32x4 __attribute__((ext_vector_type(4)));

__device__ __forceinline__ unsigned int pk4fp8(float a, float b, float c, float d) {
  int r = __builtin_amdgcn_cvt_pk_fp8_f32(a, b, 0, false);
  r = __builtin_amdgcn_cvt_pk_fp8_f32(c, d, r, true);
  return (unsigned int)r;
}

// ---------------- gating: logits = X @ WG, softmax-max + argmax ----------------
template<int E>
__global__ __launch_bounds__(256)
void gate_kernel(const float* __restrict__ X, const float* __restrict__ WG,
                 int* __restrict__ idxO, float* __restrict__ gateO) {
  const int tid  = threadIdx.x;
  const int lane = tid & 63;
  const int wv   = tid >> 6;
  const int t    = blockIdx.x * 4 + wv;
  const float* xr = X + (size_t)t * D_;
  float acc[E];
#pragma unroll
  for (int e = 0; e < E; ++e) acc[e] = 0.f;
#pragma unroll
  for (int i = 0; i < 4; ++i) {
    float4 xv = *(const float4*)(xr + i * 256 + lane * 4);
    int kb = i * 256 + lane * 4;
#pragma unroll
    for (int j = 0; j < 4; ++j) {
      float xs = (&xv.x)[j];
      const float* wr = WG + (size_t)(kb + j) * E;
#pragma unroll
      for (int e = 0; e < E; ++e) acc[e] += xs * wr[e];
    }
  }
#pragma unroll
  for (int e = 0; e < E; ++e) {
    float v = acc[e];
#pragma unroll
    for (int s = 32; s >= 1; s >>= 1) v += __shfl_xor(v, s, 64);
    acc[e] = v;
  }
  if (lane == 0) {
    float mx = acc[0]; int mi = 0;
#pragma unroll
    for (int e = 1; e < E; ++e) if (acc[e] > mx) { mx = acc[e]; mi = e; }
    float s = 0.f;
#pragma unroll
    for (int e = 0; e < E; ++e) s += expf(acc[e] - mx);
    idxO[t]  = mi;
    gateO[t] = 1.0f / s;   // max softmax prob
  }
}

// ---------------- order-preserving per-expert position scan ----------------
__global__ __launch_bounds__(1024)
void scan_kernel(const int* __restrict__ idx, int E, int cap,
                 int* __restrict__ pos, int* __restrict__ kept) {
  __shared__ int cnt[16][17];
  __shared__ int gbase[16];
  const int tid = threadIdx.x;
  const int w = tid >> 6, lane = tid & 63;
  if (tid < E) gbase[tid] = 0;
  __syncthreads();
  const unsigned long long lt = (lane == 63) ? 0xFFFFFFFFFFFFFFFFull >> 1
                                             : ((1ull << lane) - 1ull);
  for (int it = 0; it < T_ / 1024; ++it) {
    int t = it * 1024 + tid;
    int mi = idx[t];
    int rank = 0;
    for (int e = 0; e < E; ++e) {
      unsigned long long m = __ballot(mi == e);
      if (lane == 0) cnt[w][e] = __popcll(m);
      if (mi == e) rank = __popcll(m & lt);
    }
    __syncthreads();
    int off = 0;
    for (int w2 = 0; w2 < w; ++w2) off += cnt[w2][mi];
    pos[t] = gbase[mi] + off + rank;
    __syncthreads();
    if (tid < E) {
      int tot = 0;
      for (int w2 = 0; w2 < 16; ++w2) tot += cnt[w2][tid];
      gbase[tid] += tot;
    }
    __syncthreads();
  }
  if (tid < E) kept[tid] = min(gbase[tid], cap);
}

// -- scatter tokens to expert buffers (f32 -> fp8); zero m-row for DROPPED only -
__global__ __launch_bounds__(256)
void scatter_kernel(const float* __restrict__ X, const int* __restrict__ idx,
                    const int* __restrict__ pos, int cap,
                    unsigned char* __restrict__ xbuf, int* __restrict__ tokmap,
                    float* __restrict__ mzero) {
  const int t = blockIdx.x * 4 + (threadIdx.x >> 6);
  const int lane = threadIdx.x & 63;
  const int p = pos[t];
  if (p < cap) {
    const size_t dst = ((size_t)idx[t] * cap + p) * D_;
    const float* xr = X + (size_t)t * D_;
#pragma unroll
    for (int i = 0; i < 4; ++i) {
      float4 v = *(const float4*)(xr + i * 256 + lane * 4);
      *(unsigned int*)(xbuf + dst + i * 256 + lane * 4) = pk4fp8(v.x, v.y, v.z, v.w);
    }
    if (lane == 0) tokmap[(size_t)idx[t] * cap + p] = t;
  } else {
    float4 z = {0.f, 0.f, 0.f, 0.f};
    float* mr = mzero + (size_t)t * D_;
#pragma unroll
    for (int i = 0; i < 4; ++i) *(float4*)(mr + i * 256 + lane * 4) = z;
  }
}

// --------- weight transpose+convert: [K][N] f32 -> [N][K] fp8 e4m3 ------------
__global__ __launch_bounds__(256)
void wtrans_kernel(const float* __restrict__ src, unsigned char* __restrict__ dst,
                   int K, int N) {
  __shared__ float t[64][65];
  const int tid = threadIdx.x;
  const size_t eo = (size_t)blockIdx.z * K * N;
  const int k0 = blockIdx.y * 64, n0 = blockIdx.x * 64;
  const float* s = src + eo + (size_t)k0 * N + n0;
  unsigned char* d = dst + eo + (size_t)n0 * K + k0;
#pragma unroll
  for (int i = 0; i < 4; ++i) {
    int k = i * 16 + (tid >> 4);
    int n4 = (tid & 15) * 4;
    float4 v = *(const float4*)(s + (size_t)k * N + n4);
    t[k][n4] = v.x; t[k][n4 + 1] = v.y; t[k][n4 + 2] = v.z; t[k][n4 + 3] = v.w;
  }
  __syncthreads();
#pragma unroll
  for (int i = 0; i < 4; ++i) {
    int n = i * 16 + (tid >> 4);
    int k4 = (tid & 15) * 4;
    *(unsigned int*)(d + (size_t)n * K + k4) =
        pk4fp8(t[k4][n], t[k4 + 1][n], t[k4 + 2][n], t[k4 + 3][n]);
  }
}

// ---------------- expert GEMM: 256x256 tile, fp8 BK=128, 8-phase counted-vmcnt -
// GEMM path identical to rounds 14/15/17 (absmax-0.0 verified). Worker blocks:
//  - tsrc != null: transpose next weight f32 -> fp8 (512-thr indexing, r15-verified).
//  - xsrc != null: pre-accumulate residual x-mean into sentx (backfills GEMM1_2).
#define STG(BASEPTR, H, KT, SLOT) do {                                          \
    const unsigned char* _s = (BASEPTR) + (size_t)((H) * 128) * K + (KT) + st_off; \
    __builtin_amdgcn_global_load_lds((const __attribute__((address_space(1))) void*)_s, \
        (__attribute__((address_space(3))) void*)(smem + (SLOT) + dst0), 16, 0, 0);   \
    __builtin_amdgcn_global_load_lds((const __attribute__((address_space(1))) void*)(_s + (size_t)64 * K), \
        (__attribute__((address_space(3))) void*)(smem + (SLOT) + 8192 + dst0), 16, 0, 0); \
  } while (0)

#define RDA(BUF, MH) do { _Pragma("unroll")                                     \
    for (int m_ = 0; m_ < 4; ++m_) {                                            \
      const char* _p = smem + (BUF) * 65536 + aslot + ((MH) * 4 + m_) * 2048 + vaf; \
      _Pragma("unroll") for (int k_ = 0; k_ < 4; ++k_)                          \
        af[m_][k_] = *(const long long*)(_p + (((2 * k_ + c0) ^ swz7) << 4)); } } while (0)

#define RDB01(BUF, DEST) do { _Pragma("unroll")                                 \
    for (int j_ = 0; j_ < 2; ++j_) {                                            \
      const char* _p = smem + (BUF) * 65536 + bslot + j_ * 2048 + vbf;          \
      _Pragma("unroll") for (int k_ = 0; k_ < 4; ++k_)                          \
        DEST[j_][k_] = *(const long long*)(_p + (((2 * k_ + c0) ^ swz7) << 4)); } } while (0)

#define RDB23(BUF) do { _Pragma("unroll")                                       \
    for (int j_ = 0; j_ < 2; ++j_) {                                            \
      const char* _p = smem + (BUF) * 65536 + bslot + (2 + j_) * 2048 + vbf;    \
      _Pragma("unroll") for (int k_ = 0; k_ < 4; ++k_)                          \
        bfb[j_][k_] = *(const long long*)(_p + (((2 * k_ + c0) ^ swz7) << 4)); } } while (0)

#define QUADN0(MH, BA) do {                                                     \
    __builtin_amdgcn_s_setprio(1);                                              \
    _Pragma("unroll") for (int m_ = 0; m_ < 4; ++m_)                            \
    _Pragma("unroll") for (int j_ = 0; j_ < 2; ++j_)                            \
    _Pragma("unroll") for (int k_ = 0; k_ < 4; ++k_)                            \
      acc[(MH) * 4 + m_][j_] = __builtin_amdgcn_mfma_f32_16x16x32_fp8_fp8(      \
          af[m_][k_], BA[j_][k_], acc[(MH) * 4 + m_][j_], 0, 0, 0);             \
    __builtin_amdgcn_s_setprio(0);                                              \
  } while (0)

#define QUADN1(MH) do {                                                         \
    __builtin_amdgcn_s_setprio(1);                                              \
    _Pragma("unroll") for (int m_ = 0; m_ < 4; ++m_)                            \
    _Pragma("unroll") for (int j_ = 0; j_ < 2; ++j_)                            \
    _Pragma("unroll") for (int k_ = 0; k_ < 4; ++k_)                            \
      acc[(MH) * 4 + m_][2 + j_] = __builtin_amdgcn_mfma_f32_16x16x32_fp8_fp8(  \
          af[m_][k_], bfb[j_][k_], acc[(MH) * 4 + m_][2 + j_], 0, 0, 0);        \
    __builtin_amdgcn_s_setprio(0);                                              \
  } while (0)

#define SB0   __builtin_amdgcn_sched_barrier(0)
#define BAR   __builtin_amdgcn_s_barrier()
#define VM6   do { asm volatile("s_waitcnt vmcnt(6)" ::: "memory"); SB0; } while (0)
#define VM8   do { asm volatile("s_waitcnt vmcnt(8)" ::: "memory"); SB0; } while (0)
#define VM0   do { asm volatile("s_waitcnt vmcnt(0)" ::: "memory"); SB0; } while (0)

template<int MODE>
__global__ __launch_bounds__(512, 2)
void moe_gemm(const unsigned char* __restrict__ A,
              const unsigned char* __restrict__ BT,
              const float* __restrict__ bias, int K, int N, int cap, int nbcnt,
              int ntl,
              const int* __restrict__ kept,
              unsigned char* __restrict__ Hout, float* __restrict__ Mout,
              const int* __restrict__ tokmap, const float* __restrict__ gate,
              const float* __restrict__ tsrc, unsigned char* __restrict__ tdst,
              int tK, int tN, int tE,
              const float* __restrict__ xsrc, float* __restrict__ sentx,
              int nwrk) {
  __shared__ char smem[131072];
  const int tid  = threadIdx.x;

  // ---- transpose-worker blocks (co-run with GEMM blocks; 512-thr indexing) ----
  if (tsrc != nullptr && (int)blockIdx.x < nwrk) {
    const int ntn = tN >> 7, ntk = tK >> 7;
    const int tiles = tE * ntk * ntn;
    const int krow = tid >> 2;            // 0..127
    const int kq   = (tid & 3) * 32;      // 32-elem quarter
    for (int t = blockIdx.x; t < tiles; t += nwrk) {
      const int e2 = t / (ntk * ntn), rm = t - e2 * (ntk * ntn);
      const int k0 = (rm / ntn) << 7, n0 = (rm - (rm / ntn) * ntn) << 7;
      const float* s = tsrc + (size_t)e2 * tK * tN + (size_t)(k0 + krow) * tN + n0 + kq;
#pragma unroll
      for (int j = 0; j < 8; ++j) {
        float4 v = *(const float4*)(s + j * 4);
        unsigned int q = pk4fp8(v.x, v.y, v.z, v.w);
#pragma unroll
        for (int b = 0; b < 4; ++b)
          smem[(kq + j * 4 + b) * 128 + krow] = (char)((q >> (8 * b)) & 0xff);
      }
      __syncthreads();
      unsigned char* d = tdst + (size_t)e2 * tK * tN + (size_t)(n0 + krow) * tK + k0 + kq;
      *(uint4*)(d)      = *(const uint4*)(smem + krow * 128 + kq);
      *(uint4*)(d + 16) = *(const uint4*)(smem + krow * 128 + kq + 16);
      __syncthreads();
    }
    return;
  }

  // ---- x-mean worker blocks: sentx[b][c] += mean_s x[b][s][c] (x part) ----
  if (xsrc != nullptr && (int)blockIdx.x < nwrk) {
    const int b  = blockIdx.x >> 3;       // 0..7
    const int se = blockIdx.x & 7;        // s-eighth
    const float* xr = xsrc + ((size_t)b * S_ + (size_t)se * 256) * D_;
    float ax = 0.f, ay = 0.f;
    const int c2 = tid * 2;
    for (int s = 0; s < 256; ++s) {
      float2 v = *(const float2*)(xr + (size_t)s * D_ + c2);
      ax += v.x; ay += v.y;
    }
    atomicAdd(&sentx[b * D_ + c2],     ax * (1.0f / (float)S_));
    atomicAdd(&sentx[b * D_ + c2 + 1], ay * (1.0f / (float)S_));
    return;
  }

  const int gbid = (int)blockIdx.x - ((tsrc != nullptr || xsrc != nullptr) ? nwrk : 0);
  const int lane = tid & 63;
  const int wv   = tid >> 6;      // 0..7
  const int wr   = wv >> 2;       // 0..1 (M half)
  const int wc   = wv & 3;        // 0..3 (N quarter)

  // XCD-chunk swizzle + group-of-4-mb for L2 locality (over GEMM tiles only)
  const int wg  = (gbid & 7) * (ntl >> 3) + (gbid >> 3);
  const int per_grp = nbcnt * 4;
  const int grp = wg / per_grp;
  const int rem = wg - grp * per_grp;
  const int mb  = grp * 4 + (rem & 3);
  const int nb  = rem >> 2;

  const int e  = (mb * 256) / cap;
  const int r0 = mb * 256 - e * cap;
  const int kept_e = kept[e];
  if (r0 >= kept_e) return;
  const unsigned char* Ab = A + (size_t)(mb * 256) * K;
  const unsigned char* Bb = BT + ((size_t)e * N + (size_t)nb * 256) * K;

  f32x4 acc[8][4];
#pragma unroll
  for (int m = 0; m < 8; ++m)
#pragma unroll
    for (int n = 0; n < 4; ++n) acc[m][n] = (f32x4){0.f, 0.f, 0.f, 0.f};

  // staging: chunk row = tid>>3 (0..63), cc = tid&7; 16B chunks, src pre-swizzled
  const int scol   = ((tid & 7) ^ ((tid >> 3) & 7)) * 16;   // fp8 elements (=bytes)
  const size_t st_off = (size_t)(tid >> 3) * K + scol;
  const int dst0   = tid * 16;

  // fragment read addressing (fp8, b64 per frag)
  const int r16  = lane & 15;
  const int l34  = lane >> 4;                 // 0..3
  const int c0   = l34 >> 1;                  // chunk base within window pair
  const int swz7 = r16 & 7;
  const int vaf  = r16 * 128 + (l34 & 1) * 8;
  const int vbf  = (wc & 1) * 8192 + vaf;
  const int aslot = wr * 16384;
  const int bslot = 32768 + (wc >> 1) * 16384;
  long long af[4][4], bA0[2][4], bA1[2][4], bfb[2][4];

  // slot byte offsets: buf0 A0=0 A1=16384 B0=32768 B1=49152 ; buf1 +65536
  // prologue: stage buf0{A0,B0,B1,A1}, buf1{A0,B0,B1,A1} (K-tiles 0 and 128)
  STG(Ab, 0, 0, 0);
  STG(Bb, 0, 0, 32768);
  STG(Bb, 1, 0, 49152);
  STG(Ab, 1, 0, 16384);
  STG(Ab, 0, 128, 65536);
  STG(Bb, 0, 128, 98304);
  STG(Bb, 1, 128, 114688);
  STG(Ab, 1, 128, 81920);
  VM8; BAR;   // buf0's 8 loads landed; buf1's 8 outstanding
  RDB01(0, bA0);   // buf0 B-frags 0,1 (landed)

  const int NT = K >> 7;   // 128-wide K-tiles
  const int NI = K >> 8;   // 2 K-tiles per iteration
  for (int i = 0; i < NI; ++i) {
    const bool last = (i == NI - 1);
    const bool s2 = (2 * i + 2) < NT;   // stage tile 2i+2 (into buf0)
    const bool s3 = (2 * i + 3) < NT;   // stage tile 2i+3 (into buf1)
    const int kt1 = (2 * i + 1) << 7;
    const int kt2 = (2 * i + 2) << 7;
    const int kt3 = (2 * i + 3) << 7;

    // ph1: reads buf0.A0 (B01 already in bA0) ; stage buf1.A1 <- tile 2i+1
    RDA(0, 0);
    if (i > 0) STG(Ab, 1, kt1, 81920);
    BAR; QUADN0(0, bA0); BAR;
    // ph2: reads buf0 B-frags 2,3 ; stage buf0.A0 <- tile 2i+2
    RDB23(0);
    if (s2) STG(Ab, 0, kt2, 0);
    BAR; QUADN1(0); BAR;
    // ph3: reads buf0.A1 ; stage buf0.B0 <- tile 2i+2
    RDA(0, 1);
    if (s2) STG(Bb, 0, kt2, 32768);
    BAR; QUADN1(1); BAR;
    // ph4: stage buf0.B1 <- tile 2i+2 ; checkpoint ; pre-read buf1 B-frags 0,1
    if (s2) STG(Bb, 1, kt2, 49152);
    if (last) { VM0; } else { VM6; }
    RDB01(1, bA1);
    BAR; QUADN0(1, bA0); BAR;
    // ph5: reads buf1.A0 ; stage buf0.A1 <- tile 2i+2
    RDA(1, 0);
    if (s2) STG(Ab, 1, kt2, 16384);
    BAR; QUADN0(0, bA1); BAR;
    // ph6: reads buf1 B-frags 2,3 ; stage buf1.A0 <- tile 2i+3
    RDB23(1);
    if (s3) STG(Ab, 0, kt3, 65536);
    BAR; QUADN1(0); BAR;
    // ph7: reads buf1.A1 ; stage buf1.B0 <- tile 2i+3
    RDA(1, 1);
    if (s3) STG(Bb, 0, kt3, 98304);
    BAR; QUADN1(1); BAR;
    // ph8: stage buf1.B1 <- tile 2i+3 ; checkpoint ; pre-read buf0 B-frags 0,1
    if (s3) STG(Bb, 1, kt3, 114688);
    if (!last) { VM6; RDB01(0, bA0); }
    BAR; QUADN0(1, bA1); BAR;
  }

  // epilogue
  const int rg = lane >> 4;
  float bv[4];
#pragma unroll
  for (int n = 0; n < 4; ++n)
    bv[n] = bias[(size_t)e * N + nb * 256 + wc * 64 + n * 16 + r16];

#pragma unroll
  for (int m = 0; m < 8; ++m) {
#pragma unroll
    for (int r = 0; r < 4; ++r) {
      const int lrow = wr * 128 + m * 16 + rg * 4 + r;
      if (MODE == 0) {
        unsigned char* orow = Hout + (size_t)(mb * 256 + lrow) * N + nb * 256;
        unsigned int q = pk4fp8(fmaxf(acc[m][0][r] + bv[0], 0.f),
                                fmaxf(acc[m][1][r] + bv[1], 0.f),
                                fmaxf(acc[m][2][r] + bv[2], 0.f),
                                fmaxf(acc[m][3][r] + bv[3], 0.f));
        orow[wc * 64 +  0 + r16] = (unsigned char)(q & 0xff);
        orow[wc * 64 + 16 + r16] = (unsigned char)((q >> 8) & 0xff);
        orow[wc * 64 + 32 + r16] = (unsigned char)((q >> 16) & 0xff);
        orow[wc * 64 + 48 + r16] = (unsigned char)(q >> 24);
      } else {
        const int lr = r0 + lrow;
        if (lr < kept_e) {
          const int tok = tokmap[mb * 256 + lrow];
          const float gsc = gate[tok];
          float* orow = Mout + (size_t)tok * N + nb * 256;
#pragma unroll
          for (int n = 0; n < 4; ++n)
            orow[wc * 64 + n * 16 + r16] = (acc[m][n][r] + bv[n]) * gsc;
        }
      }
    }
  }
}

// ---------------- residual mean: m2 part only (x part done by GEMM workers) ---
__global__ __launch_bounds__(256)
void reduce_kernel(const float* __restrict__ M2, float* __restrict__ sent) {
  const int c = blockIdx.x * 256 + threadIdx.x;   // 0..1023
  const int b = blockIdx.z;
  const int s0 = blockIdx.y * 128;
  float a = 0.f;
  size_t base = ((size_t)b * S_ + s0) * D_ + c;
  for (int s = 0; s < 128; ++s) a += M2[base + (size_t)s * D_];
  atomicAdd(&sent[b * D_ + c], a * (1.0f / (float)S_));
}

// ---------------- logsumexp NLL loss ----------------
__global__ __launch_bounds__(64)
void loss_kernel(const float* __restrict__ sent, const int* __restrict__ y,
                 float* __restrict__ out) {
  const int lane = threadIdx.x;
  float total = 0.f;
  for (int b = 0; b < B_; ++b) {
    const float* s = sent + b * D_;
    float v[16];
    float mx = -1e30f;
#pragma unroll
    for (int i = 0; i < 16; ++i) { v[i] = s[lane + i * 64]; mx = fmaxf(mx, v[i]); }
#pragma unroll
    for (int sh = 32; sh >= 1; sh >>= 1) mx = fmaxf(mx, __shfl_xor(mx, sh, 64));
    float sm = 0.f;
#pragma unroll
    for (int i = 0; i < 16; ++i) sm += expf(v[i] - mx);
#pragma unroll
    for (int sh = 32; sh >= 1; sh >>= 1) sm += __shfl_xor(sm, sh, 64);
    total += logf(sm) + mx - s[y[b]];
  }
  if (lane == 0) out[0] = total * (1.0f / (float)B_);
}

extern "C" void kernel_launch(void* const* d_in, const int* in_sizes, int n_in,
                              void* d_out, int out_size, void* d_ws, size_t ws_size,
                              hipStream_t stream) {
  const float* x   = (const float*)d_in[0];
  const int*   y   = (const int*)d_in[1];
  const float* wg1 = (const float*)d_in[2];
  const float* w1a = (const float*)d_in[3];
  const float* b1a = (const float*)d_in[4];
  const float* w2a = (const float*)d_in[5];
  const float* b2a = (const float*)d_in[6];
  const float* wg2 = (const float*)d_in[7];
  const float* w1b = (const float*)d_in[8];
  const float* b1b = (const float*)d_in[9];
  const float* w2b = (const float*)d_in[10];
  const float* b2b = (const float*)d_in[11];
  float* out = (float*)d_out;
  (void)in_sizes; (void)n_in; (void)out_size; (void)ws_size;

  char* base = (char*)d_ws;
  size_t o = 0;
  auto alloc = [&](size_t bytes) { size_t r = o; o = (o + bytes + 255) & ~(size_t)255; return r; };
  int*   idx1    = (int*)  (base + alloc((size_t)T_ * 4));
  int*   pos1    = (int*)  (base + alloc((size_t)T_ * 4));
  float* gate1   = (float*)(base + alloc((size_t)T_ * 4));
  int*   idx2    = (int*)  (base + alloc((size_t)T_ * 4));
  int*   pos2    = (int*)  (base + alloc((size_t)T_ * 4));
  float* gate2   = (float*)(base + alloc((size_t)T_ * 4));
  int*   kept1   = (int*)  (base + alloc(64 * 4));
  int*   kept2   = (int*)  (base + alloc(64 * 4));
  int*   tokmap1 = (int*)  (base + alloc((size_t)EC_ * 4));
  int*   tokmap2 = (int*)  (base + alloc((size_t)EC_ * 4));
  float* sent    = (float*)(base + alloc((size_t)B_ * D_ * 4));
  float* m1      = (float*)(base + alloc((size_t)T_ * D_ * 4));   // layer-1 out, reused as layer-2 out
  unsigned char* xbuf = (unsigned char*)(base + alloc((size_t)EC_ * D_));        // 20 MB fp8
  unsigned char* h    = (unsigned char*)(base + alloc((size_t)EC_ * DFF_));      // 80 MB fp8
  unsigned char* P1   = (unsigned char*)(base + alloc((size_t)E2_ * D_ * DFF_)); // 64 MB fp8
  unsigned char* P2   = (unsigned char*)(base + alloc((size_t)E2_ * D_ * DFF_)); // 64 MB fp8

  hipMemsetAsync(sent, 0, (size_t)B_ * D_ * 4, stream);

  const int NT0 = (DFF_ / 256) * (EC_ / 256);   // 1280 GEMM0 tiles
  const int NT1 = (D_  / 256) * (EC_ / 256);    // 320  GEMM1 tiles
  const int NW  = 128;                          // transpose-worker blocks

  // ----- layer 1 (E=8, cap=2560) -----
  gate_kernel<E1_><<<T_ / 4, 256, 0, stream>>>(x, wg1, idx1, gate1);
  scan_kernel<<<1, 1024, 0, stream>>>(idx1, E1_, CAP1_, pos1, kept1);
  scatter_kernel<<<T_ / 4, 256, 0, stream>>>(x, idx1, pos1, CAP1_, xbuf, tokmap1, m1);
  wtrans_kernel<<<dim3(DFF_ / 64, D_ / 64, E1_), 256, 0, stream>>>(w1a, P1, D_, DFF_);
  // GEMM0_1 reads P1(w1a^T); workers transpose w2a -> P2
  moe_gemm<0><<<NT0 + NW, 512, 0, stream>>>(
      xbuf, P1, b1a, D_, DFF_, CAP1_, DFF_ / 256, NT0, kept1, h, nullptr, nullptr, nullptr,
      w2a, P2, DFF_, D_, E1_, nullptr, nullptr, NW);
  // GEMM1_1 reads P2(w2a^T); workers transpose w1b -> P1
  moe_gemm<1><<<NT1 + NW, 512, 0, stream>>>(
      h, P2, b2a, DFF_, D_, CAP1_, D_ / 256, NT1, kept1, nullptr, m1, tokmap1, gate1,
      w1b, P1, D_, DFF_, E2_, nullptr, nullptr, NW);

  // ----- layer 2 (E=16, cap=1280) -----
  gate_kernel<E2_><<<T_ / 4, 256, 0, stream>>>(m1, wg2, idx2, gate2);
  scan_kernel<<<1, 1024, 0, stream>>>(idx2, E2_, CAP2_, pos2, kept2);
  scatter_kernel<<<T_ / 4, 256, 0, stream>>>(m1, idx2, pos2, CAP2_, xbuf, tokmap2, m1);
  // GEMM0_2 reads P1(w1b^T); workers transpose w2b -> P2
  moe_gemm<0><<<NT0 + NW, 512, 0, stream>>>(
      xbuf, P1, b1b, D_, DFF_, CAP2_, DFF_ / 256, NT0, kept2, h, nullptr, nullptr, nullptr,
      w2b, P2, DFF_, D_, E2_, nullptr, nullptr, NW);
  // GEMM1_2 reads P2(w2b^T); workers pre-accumulate x-mean into sent
  moe_gemm<1><<<NT1 + 64, 512, 0, stream>>>(
      h, P2, b2b, DFF_, D_, CAP2_, D_ / 256, NT1, kept2, nullptr, m1, tokmap2, gate2,
      nullptr, nullptr, 0, 0, 0, x, sent, 64);

  // ----- residual (m2 part) + loss -----
  reduce_kernel<<<dim3(D_ / 256, S_ / 128, B_), 256, 0, stream>>>(m1, sent);
  loss_kernel<<<1, 64, 0, stream>>>(sent, y, out);
}